// Round 11
// baseline (255.840 us; speedup 1.0000x reference)
//
#include <hip/hip_runtime.h>
#include <hip/hip_bf16.h>
#include <math.h>

#define DIMC   1024
#define NHEADS 16
#define HDIM   64
#define BATCH  2
#define SEQ    2048
#define SCALE  0.125f
// q pre-scale: SCALE * log2(e)  -> scores in exp2 domain
#define QSCL   (0.125f * 1.44269504088896341f)

typedef unsigned short u16;
typedef unsigned int   u32;
typedef __attribute__((ext_vector_type(8))) short bf16x8;   // 8 bf16 = 4 VGPRs
typedef __attribute__((ext_vector_type(4))) float f32x4;

// [B][H][N][D] per tensor, element count
#define BHND ((size_t)BATCH * NHEADS * SEQ * HDIM)   // 4,194,304
#define MROWS ((size_t)BATCH * SEQ)                  // 4096

__device__ __forceinline__ u16 f2bf(float x) {
    __hip_bfloat16 h = __float2bfloat16(x);
    return *reinterpret_cast<u16*>(&h);
}
__device__ __forceinline__ float bf2f(u16 x) {
    unsigned int u = ((unsigned int)x) << 16;
    return __uint_as_float(u);
}
__device__ __forceinline__ void gload_lds16(const u16* g, u16* l) {
    __builtin_amdgcn_global_load_lds(
        (const __attribute__((address_space(1))) unsigned int*)g,
        (__attribute__((address_space(3))) unsigned int*)l, 16, 0, 0);
}

// ---------------------------------------------------------------------------
// Prepass 1: elementwise split fp32 -> bf16 hi + lo  (hi+lo ~= x to 2^-17)
// ---------------------------------------------------------------------------
__global__ __launch_bounds__(256) void splita_kernel(
    const float* __restrict__ in, u16* __restrict__ hi, u16* __restrict__ lo)
{
    int i = (blockIdx.x * 256 + threadIdx.x) * 8;
    float4 a = *(const float4*)&in[i];
    float4 b = *(const float4*)&in[i + 4];
    float v[8] = {a.x, a.y, a.z, a.w, b.x, b.y, b.z, b.w};
    bf16x8 vh, vl;
    #pragma unroll
    for (int j = 0; j < 8; ++j) {
        u16 h = f2bf(v[j]);
        vh[j] = (short)h;
        vl[j] = (short)f2bf(v[j] - bf2f(h));
    }
    *(bf16x8*)&hi[i] = vh;
    *(bf16x8*)&lo[i] = vl;
}

// ---------------------------------------------------------------------------
// Prepass 2: W [K][N] fp32 -> transposed split bf16  Thi/Tlo [N][K]
// ---------------------------------------------------------------------------
__global__ __launch_bounds__(256) void splitw_kernel(
    const float* __restrict__ W, u16* __restrict__ Thi, u16* __restrict__ Tlo,
    int K, int N)
{
    __shared__ float Ws[64][65];
    const int kb  = blockIdx.x * 64;
    const int nb  = blockIdx.y * 64;
    const int tid = threadIdx.x;
    const int jr  = (tid & 15) * 4;
    const int ir  = tid >> 4;
    #pragma unroll
    for (int it = 0; it < 4; ++it) {
        int i = ir + it * 16;
        *(float4*)&Ws[i][jr] = *(const float4*)&W[(size_t)(kb + i) * N + nb + jr];
    }
    __syncthreads();
    const int n  = tid >> 2;
    const int k0 = (tid & 3) * 16;
    bf16x8 h0, h1, l0, l1;
    #pragma unroll
    for (int kk = 0; kk < 8; ++kk) {
        float x = Ws[k0 + kk][n];
        u16 h = f2bf(x);
        h0[kk] = (short)h; l0[kk] = (short)f2bf(x - bf2f(h));
        float y = Ws[k0 + 8 + kk][n];
        u16 h2 = f2bf(y);
        h1[kk] = (short)h2; l1[kk] = (short)f2bf(y - bf2f(h2));
    }
    size_t off = (size_t)(nb + n) * K + kb + k0;
    *(bf16x8*)&Thi[off]     = h0;
    *(bf16x8*)&Thi[off + 8] = h1;
    *(bf16x8*)&Tlo[off]     = l0;
    *(bf16x8*)&Tlo[off + 8] = l1;
}

// ---------------------------------------------------------------------------
// Split-bf16 MFMA GEMM. 128x128 tile, BK=32, 4 waves x (64x64),
// global_load_lds staging, 3 MFMAs per fragment pair.
// MODE 0: scatter bf16 q(*QSCL, exp2 domain)/k [B][H][N][D],
//         v^T PRE-MASKED by mask[key] [B][H][D][N]
// MODE 1: + bias, fp32 store to out[M][N]
// ---------------------------------------------------------------------------
template <int MODE>
__global__ __launch_bounds__(256) void gemm_split_kernel(
    const u16* __restrict__ Ahi, const u16* __restrict__ Alo,
    const u16* __restrict__ Bhi, const u16* __restrict__ Blo,
    const float* __restrict__ bias, const float* __restrict__ vmask,
    float* __restrict__ outf, u16* __restrict__ outb,
    int M, int N, int K)
{
    __shared__ __align__(16) u16 lds[4][128 * 32];   // Ahi, Alo, BhiT, BloT

    const int bm   = blockIdx.y * 128;
    const int bn   = blockIdx.x * 128;
    const int tid  = threadIdx.x;
    const int wid  = tid >> 6;
    const int lane = tid & 63;
    const int lo   = lane & 15;
    const int g4   = lane >> 4;
    const int wr   = wid >> 1, wc = wid & 1;

    const int mrow = lane >> 2;
    const int ks8  = (lane & 3) * 8;
    const u16* g0;
    if      (wid == 0) g0 = Ahi + (size_t)(bm + mrow) * K + ks8;
    else if (wid == 1) g0 = Alo + (size_t)(bm + mrow) * K + ks8;
    else if (wid == 2) g0 = Bhi + (size_t)(bn + mrow) * K + ks8;
    else               g0 = Blo + (size_t)(bn + mrow) * K + ks8;
    u16* lbase = &lds[wid][0];

    f32x4 acc[4][4] = {};

    for (int k0 = 0; k0 < K; k0 += 32) {
        const u16* g = g0 + k0;
        #pragma unroll
        for (int s = 0; s < 8; ++s)
            gload_lds16(g + (size_t)s * 16 * K, lbase + s * 512);
        __syncthreads();

        bf16x8 bh[4], bl[4];
        #pragma unroll
        for (int ni = 0; ni < 4; ++ni) {
            int row = wc * 64 + ni * 16 + lo;
            bh[ni] = *(const bf16x8*)&lds[2][row * 32 + g4 * 8];
            bl[ni] = *(const bf16x8*)&lds[3][row * 32 + g4 * 8];
        }
        #pragma unroll
        for (int mi = 0; mi < 4; ++mi) {
            int row = wr * 64 + mi * 16 + lo;
            bf16x8 ah = *(const bf16x8*)&lds[0][row * 32 + g4 * 8];
            bf16x8 al = *(const bf16x8*)&lds[1][row * 32 + g4 * 8];
            #pragma unroll
            for (int ni = 0; ni < 4; ++ni) {
                acc[mi][ni] = __builtin_amdgcn_mfma_f32_16x16x32_bf16(ah, bh[ni], acc[mi][ni], 0, 0, 0);
                acc[mi][ni] = __builtin_amdgcn_mfma_f32_16x16x32_bf16(ah, bl[ni], acc[mi][ni], 0, 0, 0);
                acc[mi][ni] = __builtin_amdgcn_mfma_f32_16x16x32_bf16(al, bh[ni], acc[mi][ni], 0, 0, 0);
            }
        }
        __syncthreads();
    }

    if (MODE == 0) {
        #pragma unroll
        for (int mi = 0; mi < 4; ++mi) {
            int m0 = bm + wr * 64 + mi * 16 + 4 * g4;
            #pragma unroll
            for (int ni = 0; ni < 4; ++ni) {
                int n0    = bn + wc * 64 + ni * 16;
                int which = n0 >> 10;
                int head  = (n0 & 1023) >> 6;
                int d     = (n0 & 63) + lo;
                if (which == 0) {
                    #pragma unroll
                    for (int r = 0; r < 4; ++r) {
                        int m = m0 + r, b = m >> 11, seq = m & 2047;
                        outb[(((size_t)b * NHEADS + head) * SEQ + seq) * HDIM + d] =
                            f2bf(acc[mi][ni][r] * QSCL);
                    }
                } else if (which == 1) {
                    #pragma unroll
                    for (int r = 0; r < 4; ++r) {
                        int m = m0 + r, b = m >> 11, seq = m & 2047;
                        outb[BHND + (((size_t)b * NHEADS + head) * SEQ + seq) * HDIM + d] =
                            f2bf(acc[mi][ni][r]);
                    }
                } else {
                    int b = m0 >> 11, seq0 = m0 & 2047;   // r=0..3 same batch
                    float4 mv = *(const float4*)&vmask[b * SEQ + seq0];
                    ushort4 o;
                    o.x = f2bf(acc[mi][ni][0] * mv.x);
                    o.y = f2bf(acc[mi][ni][1] * mv.y);
                    o.z = f2bf(acc[mi][ni][2] * mv.z);
                    o.w = f2bf(acc[mi][ni][3] * mv.w);
                    *(ushort4*)&outb[2 * BHND +
                        (((size_t)b * NHEADS + head) * HDIM + d) * SEQ + seq0] = o;
                }
            }
        }
    } else {
        #pragma unroll
        for (int ni = 0; ni < 4; ++ni) {
            int col = bn + wc * 64 + ni * 16 + lo;
            float bv = bias[col];
            #pragma unroll
            for (int mi = 0; mi < 4; ++mi) {
                int m0 = bm + wr * 64 + mi * 16 + 4 * g4;
                #pragma unroll
                for (int r = 0; r < 4; ++r)
                    outf[(size_t)(m0 + r) * N + col] = acc[mi][ni][r] + bv;
            }
        }
    }
}

// ---------------------------------------------------------------------------
// MFMA flash attention, KVBLK=64, swapped QK^T (S^T = mfma(K,Q): full S-row
// for q = lane&15 held in-lane). Mask folded into V (denominator raw-p),
// exp2 domain, P redistributed in registers. FIX vs round 10: the pk[]
// fragment selection (kt = 2ks + gh) uses the DESTINATION lane's gh, so both
// gh-candidates are shuffled and selected after (prev code selected on the
// source lane, where gh_src == gl_dest -> wrong for g in {1,2}).
// ---------------------------------------------------------------------------
__global__ __launch_bounds__(256) void attn_mfma_kernel(
    const u16* __restrict__ qb, const u16* __restrict__ kb,
    const u16* __restrict__ vtb, const float* __restrict__ mask,
    u16* __restrict__ ohi, u16* __restrict__ olo)
{
    __shared__ __align__(16) u16 Ks[64 * 64];       // [key][d] swizzled
    __shared__ __align__(16) u16 Vt[64 * 64];       // [d][key] swizzled

    const int bid  = blockIdx.x;          // 1024 = B*H*(SEQ/64)
    const int qt   = bid & 31;
    const int h    = (bid >> 5) & 15;
    const int b    = bid >> 9;
    const int tid  = threadIdx.x;
    const int wid  = tid >> 6;
    const int lane = tid & 63;
    const int lo   = lane & 15;
    const int g    = lane >> 4;
    const int gh   = g >> 1, gl = g & 1;

    const size_t bh = (size_t)b * NHEADS + h;
    const int qbase = qt * 64 + wid * 16;

    // Q fragment (B operand of swapped QK^T): col = q = qbase+lo
    const u16* qrowp = qb + (bh * SEQ + qbase + lo) * HDIM + 8 * g;
    const bf16x8 aq0 = *(const bf16x8*)(qrowp);
    const bf16x8 aq1 = *(const bf16x8*)(qrowp + 32);

    // staging: 64x64 tiles, thread -> row = tid>>2, two 8-elem slots
    const int srow  = tid >> 2;
    const int scol  = (tid & 3) * 16;
    const int swz   = (srow & 7) << 3;
    const int idx0  = srow * 64 + (scol ^ swz);
    const int idx1  = srow * 64 + ((scol + 8) ^ swz);
    const u16* kgp  = kb  + (bh * SEQ  + srow) * HDIM + scol;   // + k0*HDIM
    const u16* vgp  = vtb + (bh * HDIM + srow) * SEQ  + scol;   // + k0

    f32x4 acc[4] = {};            // O[q = 4g+r][d = 16dt+lo]
    float mrun = -1e30f, lrun = 0.f;   // softmax state for q = lo (exp2 dom)

    for (int k0 = 0; k0 < SEQ; k0 += 64) {
        __syncthreads();
        *(bf16x8*)&Ks[idx0] = *(const bf16x8*)(kgp + (size_t)k0 * HDIM);
        *(bf16x8*)&Ks[idx1] = *(const bf16x8*)(kgp + (size_t)k0 * HDIM + 8);
        *(bf16x8*)&Vt[idx0] = *(const bf16x8*)(vgp + k0);
        *(bf16x8*)&Vt[idx1] = *(const bf16x8*)(vgp + k0 + 8);
        __syncthreads();

        // swapped QK^T: s[kt][r] = S^T[key = 16kt+4g+r][q = lo]
        f32x4 s[4];
        #pragma unroll
        for (int kt = 0; kt < 4; ++kt) {
            int key  = lo + 16 * kt;
            int kbse = key * 64;
            int ksw  = (key & 7) << 3;
            f32x4 t = {};
            t = __builtin_amdgcn_mfma_f32_16x16x32_bf16(*(const bf16x8*)&Ks[kbse + ((8 * g) ^ ksw)], aq0, t, 0, 0, 0);
            t = __builtin_amdgcn_mfma_f32_16x16x32_bf16(*(const bf16x8*)&Ks[kbse + ((32 + 8 * g) ^ ksw)], aq1, t, 0, 0, 0);
            s[kt] = t;
        }

        // row softmax for q = lo: in-lane + 2 shfl_xor (exp2 domain)
        float rm = s[0][0];
        #pragma unroll
        for (int kt = 0; kt < 4; ++kt)
            #pragma unroll
            for (int r = 0; r < 4; ++r) rm = fmaxf(rm, s[kt][r]);
        rm = fmaxf(rm, __shfl_xor(rm, 16));
        rm = fmaxf(rm, __shfl_xor(rm, 32));

        if (!__all(rm <= mrun)) {            // bit-exact skip (corr==1 if skipped)
            float mnew = fmaxf(mrun, rm);
            float corr = exp2f(mrun - mnew);
            mrun = mnew;
            lrun *= corr;
            #pragma unroll
            for (int r = 0; r < 4; ++r) {
                float cq = __shfl(corr, 4 * g + r);   // corr for q = 4g+r
                #pragma unroll
                for (int dt = 0; dt < 4; ++dt) acc[dt][r] *= cq;
            }
        }

        float ps = 0.f;
        float p[4][4];
        #pragma unroll
        for (int kt = 0; kt < 4; ++kt)
            #pragma unroll
            for (int r = 0; r < 4; ++r) {
                p[kt][r] = exp2f(s[kt][r] - mrun);
                ps += p[kt][r];              // UNMASKED denominator
            }
        ps += __shfl_xor(ps, 16);
        ps += __shfl_xor(ps, 32);
        lrun += ps;

        // pack p -> 8 u32 (bf16 pairs along key): pk[2kt+t] = keys 16kt+4g+{2t,2t+1}
        u32 pk[8];
        #pragma unroll
        for (int kt = 0; kt < 4; ++kt) {
            pk[2 * kt]     = (u32)f2bf(p[kt][0]) | ((u32)f2bf(p[kt][1]) << 16);
            pk[2 * kt + 1] = (u32)f2bf(p[kt][2]) | ((u32)f2bf(p[kt][3]) << 16);
        }

        // redistribute to PV A-frag layout in registers.
        // frag ks, u32 j needs keys (32ks + 8g + 2j, +1) for q = lo:
        //   source lane = lo + 16*(2*gl + (j>>1))   [g' of owner]
        //   source pk index = 4ks + 2*gh_DEST + (j&1)  -> shuffle both
        //   gh-candidates, select with this lane's gh AFTER the shuffle.
        union { u32 u[4]; bf16x8 v; } fa0, fa1;
        #pragma unroll
        for (int j = 0; j < 4; ++j) {
            int src = lo + 16 * (2 * gl + (j >> 1));
            u32 c0 = (u32)__shfl((int)pk[(j & 1)],     src);
            u32 c1 = (u32)__shfl((int)pk[2 + (j & 1)], src);
            u32 c2 = (u32)__shfl((int)pk[4 + (j & 1)], src);
            u32 c3 = (u32)__shfl((int)pk[6 + (j & 1)], src);
            fa0.u[j] = gh ? c1 : c0;
            fa1.u[j] = gh ? c3 : c2;
        }

        // PV: O += P[16,64] @ V_masked[64,64]
        #pragma unroll
        for (int dt = 0; dt < 4; ++dt) {
            int vbse = (lo + 16 * dt) * 64;
            int vsw  = (lo & 7) << 3;
            acc[dt] = __builtin_amdgcn_mfma_f32_16x16x32_bf16(fa0.v, *(const bf16x8*)&Vt[vbse + ((8 * g) ^ vsw)], acc[dt], 0, 0, 0);
            acc[dt] = __builtin_amdgcn_mfma_f32_16x16x32_bf16(fa1.v, *(const bf16x8*)&Vt[vbse + ((32 + 8 * g) ^ vsw)], acc[dt], 0, 0, 0);
        }
    }

    // epilogue: pull 1/l to the acc layout, split bf16 O for the proj GEMM
    const float inv = 1.f / lrun;
    #pragma unroll
    for (int r = 0; r < 4; ++r) {
        float invq = __shfl(inv, 4 * g + r);
        size_t row = (size_t)b * SEQ + qbase + 4 * g + r;
        u16* dh = ohi + row * DIMC + h * HDIM + lo;
        u16* dl = olo + row * DIMC + h * HDIM + lo;
        #pragma unroll
        for (int dt = 0; dt < 4; ++dt) {
            float o = acc[dt][r] * invq;
            u16 hv = f2bf(o);
            dh[16 * dt] = hv;
            dl[16 * dt] = f2bf(o - bf2f(hv));
        }
    }
}

__global__ void mask_sqrt_kernel(const float* __restrict__ mask,
                                 float* __restrict__ out, int n)
{
    int i = blockIdx.x * 256 + threadIdx.x;
    if (i < n) out[i] = sqrtf(mask[i]);
}

// ---------------------------------------------------------------------------
extern "C" void kernel_launch(void* const* d_in, const int* in_sizes, int n_in,
                              void* d_out, int out_size, void* d_ws, size_t ws_size,
                              hipStream_t stream)
{
    const float* h      = (const float*)d_in[0];   // [2,2048,1024]
    const float* mask   = (const float*)d_in[1];   // [2,2048]
    const float* w_qkv  = (const float*)d_in[2];   // [1024,3072]
    const float* w_proj = (const float*)d_in[3];   // [1024,1024]
    const float* b_proj = (const float*)d_in[4];   // [1024]
    float* out = (float*)d_out;

    // ws layout (u16 units), ~59 MB total
    u16* w    = (u16*)d_ws;
    u16* qkv  = w;                                  // 3*BHND
    u16* wqh  = qkv + 3 * BHND;                     // 3072*1024
    u16* wql  = wqh + (size_t)3072 * 1024;
    u16* wph  = wql + (size_t)3072 * 1024;          // 1024*1024
    u16* wpl  = wph + (size_t)1024 * 1024;
    u16* ahi  = wpl + (size_t)1024 * 1024;          // 4096*1024 (h split; later O split)
    u16* alo  = ahi + MROWS * DIMC;

    // prepasses: split h; split+transpose weights
    splita_kernel<<<(MROWS * DIMC) / (256 * 8), 256, 0, stream>>>(h, ahi, alo);
    splitw_kernel<<<dim3(16, 48), 256, 0, stream>>>(w_qkv, wqh, wql, DIMC, 3 * DIMC);
    splitw_kernel<<<dim3(16, 16), 256, 0, stream>>>(w_proj, wph, wpl, DIMC, DIMC);

    // 1) qkv projection -> bf16 q(exp2-scaled)/k [B][H][N][D], masked v^T [B][H][D][N]
    gemm_split_kernel<0><<<dim3(24, 32), 256, 0, stream>>>(
        ahi, alo, wqh, wql, nullptr, mask, nullptr, qkv, MROWS, 3 * DIMC, DIMC);

    // 2) MFMA flash attention (swapped QK^T, register-P fixed, masked V) -> split O
    attn_mfma_kernel<<<BATCH * NHEADS * (SEQ / 64), 256, 0, stream>>>(
        qkv, qkv + BHND, qkv + 2 * BHND, mask, ahi, alo);

    // 3) output projection + bias (split MFMA, fp32 out)
    gemm_split_kernel<1><<<dim3(8, 32), 256, 0, stream>>>(
        ahi, alo, wph, wpl, b_proj, nullptr, out, nullptr, MROWS, DIMC, DIMC);

    // 4) new_mask = sqrt(mask)
    mask_sqrt_kernel<<<(BATCH * SEQ + 255) / 256, 256, 0, stream>>>(
        mask, out + MROWS * DIMC, BATCH * SEQ);
}

// Round 12
// 170.309 us; speedup vs baseline: 1.5022x; 1.5022x over previous
//
#include <hip/hip_runtime.h>
#include <hip/hip_bf16.h>
#include <math.h>

#define DIMC   1024
#define NHEADS 16
#define HDIM   64
#define BATCH  2
#define SEQ    2048
#define SCALE  0.125f
// q pre-scale: SCALE * log2(e)  -> scores in exp2 domain
#define QSCL   (0.125f * 1.44269504088896341f)

typedef unsigned short u16;
typedef unsigned int   u32;
typedef __attribute__((ext_vector_type(8))) short bf16x8;    // 8 bf16 = 4 VGPRs
typedef _Float16 f16x8 __attribute__((ext_vector_type(8)));  // 8 fp16 = 4 VGPRs
typedef __attribute__((ext_vector_type(4))) float f32x4;

// [B][H][N][D] per tensor, element count
#define BHND ((size_t)BATCH * NHEADS * SEQ * HDIM)   // 4,194,304
#define MROWS ((size_t)BATCH * SEQ)                  // 4096

__device__ __forceinline__ u16 f2bf(float x) {
    __hip_bfloat16 h = __float2bfloat16(x);
    return *reinterpret_cast<u16*>(&h);
}
__device__ __forceinline__ u16 f2h(float x) {
    _Float16 h = (_Float16)x;
    return *reinterpret_cast<u16*>(&h);
}
__device__ __forceinline__ void gload_lds16(const u16* g, u16* l) {
    __builtin_amdgcn_global_load_lds(
        (const __attribute__((address_space(1))) unsigned int*)g,
        (__attribute__((address_space(3))) unsigned int*)l, 16, 0, 0);
}

// ---------------------------------------------------------------------------
// Prepass 1: h fp32 -> fp16 A [M][K]
// ---------------------------------------------------------------------------
__global__ __launch_bounds__(256) void prep_h_kernel(
    const float* __restrict__ in, u16* __restrict__ outh)
{
    int i = (blockIdx.x * 256 + threadIdx.x) * 8;
    float4 a = *(const float4*)&in[i];
    float4 b = *(const float4*)&in[i + 4];
    float v[8] = {a.x, a.y, a.z, a.w, b.x, b.y, b.z, b.w};
    bf16x8 o;
    #pragma unroll
    for (int j = 0; j < 8; ++j) o[j] = (short)f2h(v[j]);
    *(bf16x8*)&outh[i] = o;
}

// ---------------------------------------------------------------------------
// Prepass 2: W [K][N] fp32 -> transposed fp16 W^T [N][K]
// ---------------------------------------------------------------------------
__global__ __launch_bounds__(256) void prep_w_kernel(
    const float* __restrict__ W, u16* __restrict__ T, int K, int N)
{
    __shared__ float Ws[64][65];
    const int kb  = blockIdx.x * 64;
    const int nb  = blockIdx.y * 64;
    const int tid = threadIdx.x;
    const int jr  = (tid & 15) * 4;
    const int ir  = tid >> 4;
    #pragma unroll
    for (int it = 0; it < 4; ++it) {
        int i = ir + it * 16;
        *(float4*)&Ws[i][jr] = *(const float4*)&W[(size_t)(kb + i) * N + nb + jr];
    }
    __syncthreads();
    const int n  = tid >> 2;
    const int k0 = (tid & 3) * 16;
    bf16x8 h0, h1;
    #pragma unroll
    for (int kk = 0; kk < 8; ++kk) {
        h0[kk] = (short)f2h(Ws[k0 + kk][n]);
        h1[kk] = (short)f2h(Ws[k0 + 8 + kk][n]);
    }
    size_t off = (size_t)(nb + n) * K + kb + k0;
    *(bf16x8*)&T[off]     = h0;
    *(bf16x8*)&T[off + 8] = h1;
}

// ---------------------------------------------------------------------------
// fp16 MFMA GEMM: C = A[M][K] @ W (W^T given [N][K]). 128x128 tile, BK=32,
// 4 waves x (64x64), global_load_lds staging, ONE MFMA per fragment pair.
// MODE 0: scatter bf16 q(*QSCL, exp2 domain)/k [B][H][N][D],
//         v^T PRE-MASKED by mask[key] [B][H][D][N]
// MODE 1: + bias, fp32 store to out[M][N]
// ---------------------------------------------------------------------------
template <int MODE>
__global__ __launch_bounds__(256) void gemm_f16_kernel(
    const u16* __restrict__ A, const u16* __restrict__ B,
    const float* __restrict__ bias, const float* __restrict__ vmask,
    float* __restrict__ outf, u16* __restrict__ outb,
    int M, int N, int K)
{
    __shared__ __align__(16) u16 lds[2][128 * 32];   // A tile, B^T tile

    const int bm   = blockIdx.y * 128;
    const int bn   = blockIdx.x * 128;
    const int tid  = threadIdx.x;
    const int wid  = tid >> 6;
    const int lane = tid & 63;
    const int lo   = lane & 15;
    const int g4   = lane >> 4;
    const int wr   = wid >> 1, wc = wid & 1;

    // staging: wave 0/1 -> A rows 0-63/64-127; wave 2/3 -> B rows
    const int mrow = lane >> 2;            // 0..15
    const int ks8  = (lane & 3) * 8;
    const u16* g0  = (wid < 2)
        ? A + (size_t)(bm + (wid & 1) * 64 + mrow) * K + ks8
        : B + (size_t)(bn + (wid & 1) * 64 + mrow) * K + ks8;
    u16* lbase = &lds[wid >> 1][(wid & 1) * 64 * 32];

    f32x4 acc[4][4] = {};

    for (int k0 = 0; k0 < K; k0 += 32) {
        const u16* g = g0 + k0;
        #pragma unroll
        for (int s = 0; s < 4; ++s)
            gload_lds16(g + (size_t)s * 16 * K, lbase + s * 512);
        __syncthreads();

        f16x8 bfr[4];
        #pragma unroll
        for (int ni = 0; ni < 4; ++ni)
            bfr[ni] = *(const f16x8*)&lds[1][(wc * 64 + ni * 16 + lo) * 32 + g4 * 8];
        #pragma unroll
        for (int mi = 0; mi < 4; ++mi) {
            f16x8 a = *(const f16x8*)&lds[0][(wr * 64 + mi * 16 + lo) * 32 + g4 * 8];
            #pragma unroll
            for (int ni = 0; ni < 4; ++ni)
                acc[mi][ni] = __builtin_amdgcn_mfma_f32_16x16x32_f16(a, bfr[ni], acc[mi][ni], 0, 0, 0);
        }
        __syncthreads();
    }

    if (MODE == 0) {
        #pragma unroll
        for (int mi = 0; mi < 4; ++mi) {
            int m0 = bm + wr * 64 + mi * 16 + 4 * g4;
            #pragma unroll
            for (int ni = 0; ni < 4; ++ni) {
                int n0    = bn + wc * 64 + ni * 16;
                int which = n0 >> 10;
                int head  = (n0 & 1023) >> 6;
                int d     = (n0 & 63) + lo;
                if (which == 0) {
                    #pragma unroll
                    for (int r = 0; r < 4; ++r) {
                        int m = m0 + r, b = m >> 11, seq = m & 2047;
                        outb[(((size_t)b * NHEADS + head) * SEQ + seq) * HDIM + d] =
                            f2bf(acc[mi][ni][r] * QSCL);
                    }
                } else if (which == 1) {
                    #pragma unroll
                    for (int r = 0; r < 4; ++r) {
                        int m = m0 + r, b = m >> 11, seq = m & 2047;
                        outb[BHND + (((size_t)b * NHEADS + head) * SEQ + seq) * HDIM + d] =
                            f2bf(acc[mi][ni][r]);
                    }
                } else {
                    int b = m0 >> 11, seq0 = m0 & 2047;   // r=0..3 same batch
                    float4 mv = *(const float4*)&vmask[b * SEQ + seq0];
                    ushort4 o;
                    o.x = f2bf(acc[mi][ni][0] * mv.x);
                    o.y = f2bf(acc[mi][ni][1] * mv.y);
                    o.z = f2bf(acc[mi][ni][2] * mv.z);
                    o.w = f2bf(acc[mi][ni][3] * mv.w);
                    *(ushort4*)&outb[2 * BHND +
                        (((size_t)b * NHEADS + head) * HDIM + d) * SEQ + seq0] = o;
                }
            }
        }
    } else {
        #pragma unroll
        for (int ni = 0; ni < 4; ++ni) {
            int col = bn + wc * 64 + ni * 16 + lo;
            float bv = bias[col];
            #pragma unroll
            for (int mi = 0; mi < 4; ++mi) {
                int m0 = bm + wr * 64 + mi * 16 + 4 * g4;
                #pragma unroll
                for (int r = 0; r < 4; ++r)
                    outf[(size_t)(m0 + r) * N + col] = acc[mi][ni][r] + bv;
            }
        }
    }
}

// ---------------------------------------------------------------------------
// MFMA flash attention (round-9 validated structure: LDS P-bounce, 88 us)
// + mask folded into V (denominator raw-p), exp2 domain, no Ms staging.
// Swapped QK^T: S^T = mfma(K,Q), full S-row for q = lane&15 in-lane.
// Epilogue: single fp16 O [B*SEQ][DIMC] feeding the fp16 proj GEMM.
// ---------------------------------------------------------------------------
__global__ __launch_bounds__(256) void attn_mfma_kernel(
    const u16* __restrict__ qb, const u16* __restrict__ kb,
    const u16* __restrict__ vtb, u16* __restrict__ oA)
{
    __shared__ __align__(16) u16 Ks[64 * 64];       // [key][d] swizzled
    __shared__ __align__(16) u16 Vt[64 * 64];       // [d][key] swizzled
    __shared__ __align__(16) u16 Plds[4][16 * 72];  // [wave][q][key], pad 72

    const int bid  = blockIdx.x;          // 1024 = B*H*(SEQ/64)
    const int qt   = bid & 31;
    const int h    = (bid >> 5) & 15;
    const int b    = bid >> 9;
    const int tid  = threadIdx.x;
    const int wid  = tid >> 6;
    const int lane = tid & 63;
    const int lo   = lane & 15;
    const int g    = lane >> 4;

    const size_t bh = (size_t)b * NHEADS + h;
    const int qbase = qt * 64 + wid * 16;

    // Q fragment (B operand of swapped QK^T): col = q = qbase+lo
    const u16* qrowp = qb + (bh * SEQ + qbase + lo) * HDIM + 8 * g;
    const bf16x8 aq0 = *(const bf16x8*)(qrowp);
    const bf16x8 aq1 = *(const bf16x8*)(qrowp + 32);

    // staging: 64x64 tiles, thread -> row = tid>>2, two 8-elem slots
    const int srow  = tid >> 2;
    const int scol  = (tid & 3) * 16;
    const int swz   = (srow & 7) << 3;
    const int idx0  = srow * 64 + (scol ^ swz);
    const int idx1  = srow * 64 + ((scol + 8) ^ swz);
    const u16* kgp  = kb  + (bh * SEQ  + srow) * HDIM + scol;   // + k0*HDIM
    const u16* vgp  = vtb + (bh * HDIM + srow) * SEQ  + scol;   // + k0

    f32x4 acc[4] = {};            // O[q = 4g+r][d = 16dt+lo]
    float mrun = -1e30f, lrun = 0.f;   // softmax state for q = lo (exp2 dom)

    u16* pw = &Plds[wid][0];

    for (int k0 = 0; k0 < SEQ; k0 += 64) {
        __syncthreads();
        *(bf16x8*)&Ks[idx0] = *(const bf16x8*)(kgp + (size_t)k0 * HDIM);
        *(bf16x8*)&Ks[idx1] = *(const bf16x8*)(kgp + (size_t)k0 * HDIM + 8);
        *(bf16x8*)&Vt[idx0] = *(const bf16x8*)(vgp + k0);
        *(bf16x8*)&Vt[idx1] = *(const bf16x8*)(vgp + k0 + 8);
        __syncthreads();

        // swapped QK^T: s[kt][r] = S^T[key = 16kt+4g+r][q = lo]
        f32x4 s[4];
        #pragma unroll
        for (int kt = 0; kt < 4; ++kt) {
            int key  = lo + 16 * kt;
            int kbse = key * 64;
            int ksw  = (key & 7) << 3;
            f32x4 t = {};
            t = __builtin_amdgcn_mfma_f32_16x16x32_bf16(*(const bf16x8*)&Ks[kbse + ((8 * g) ^ ksw)], aq0, t, 0, 0, 0);
            t = __builtin_amdgcn_mfma_f32_16x16x32_bf16(*(const bf16x8*)&Ks[kbse + ((32 + 8 * g) ^ ksw)], aq1, t, 0, 0, 0);
            s[kt] = t;
        }

        // row softmax for q = lo: in-lane + 2 shfl_xor (exp2 domain)
        float rm = s[0][0];
        #pragma unroll
        for (int kt = 0; kt < 4; ++kt)
            #pragma unroll
            for (int r = 0; r < 4; ++r) rm = fmaxf(rm, s[kt][r]);
        rm = fmaxf(rm, __shfl_xor(rm, 16));
        rm = fmaxf(rm, __shfl_xor(rm, 32));

        if (!__all(rm <= mrun)) {            // bit-exact skip (corr==1 if skipped)
            float mnew = fmaxf(mrun, rm);
            float corr = exp2f(mrun - mnew);
            mrun = mnew;
            lrun *= corr;
            #pragma unroll
            for (int r = 0; r < 4; ++r) {
                float cq = __shfl(corr, 4 * g + r);   // corr for q = 4g+r
                #pragma unroll
                for (int dt = 0; dt < 4; ++dt) acc[dt][r] *= cq;
            }
        }

        float ps = 0.f;
        float p[4][4];
        #pragma unroll
        for (int kt = 0; kt < 4; ++kt)
            #pragma unroll
            for (int r = 0; r < 4; ++r) {
                p[kt][r] = exp2f(s[kt][r] - mrun);
                ps += p[kt][r];              // UNMASKED denominator
            }
        ps += __shfl_xor(ps, 16);
        ps += __shfl_xor(ps, 32);
        lrun += ps;

        // raw-p numerator -> P in LDS (mask already folded into V)
        #pragma unroll
        for (int kt = 0; kt < 4; ++kt) {
            ushort4 o;
            o.x = f2bf(p[kt][0]);
            o.y = f2bf(p[kt][1]);
            o.z = f2bf(p[kt][2]);
            o.w = f2bf(p[kt][3]);
            *(ushort4*)&pw[lo * 72 + 16 * kt + 4 * g] = o;
        }

        // PV: O += P[16,64] @ V_masked[64,64]  (same-wave DS ops in-order)
        const bf16x8 pa0 = *(const bf16x8*)&pw[lo * 72 + 8 * g];
        const bf16x8 pa1 = *(const bf16x8*)&pw[lo * 72 + 32 + 8 * g];
        #pragma unroll
        for (int dt = 0; dt < 4; ++dt) {
            int vbse = (lo + 16 * dt) * 64;
            int vsw  = (lo & 7) << 3;
            acc[dt] = __builtin_amdgcn_mfma_f32_16x16x32_bf16(pa0, *(const bf16x8*)&Vt[vbse + ((8 * g) ^ vsw)], acc[dt], 0, 0, 0);
            acc[dt] = __builtin_amdgcn_mfma_f32_16x16x32_bf16(pa1, *(const bf16x8*)&Vt[vbse + ((32 + 8 * g) ^ vsw)], acc[dt], 0, 0, 0);
        }
    }

    // epilogue: pull 1/l to the acc layout, single fp16 O for the proj GEMM
    const float inv = 1.f / lrun;
    #pragma unroll
    for (int r = 0; r < 4; ++r) {
        float invq = __shfl(inv, 4 * g + r);
        size_t row = (size_t)b * SEQ + qbase + 4 * g + r;
        u16* dst = oA + row * DIMC + h * HDIM + lo;
        #pragma unroll
        for (int dt = 0; dt < 4; ++dt)
            dst[16 * dt] = f2h(acc[dt][r] * invq);
    }
}

__global__ void mask_sqrt_kernel(const float* __restrict__ mask,
                                 float* __restrict__ out, int n)
{
    int i = blockIdx.x * 256 + threadIdx.x;
    if (i < n) out[i] = sqrtf(mask[i]);
}

// ---------------------------------------------------------------------------
extern "C" void kernel_launch(void* const* d_in, const int* in_sizes, int n_in,
                              void* d_out, int out_size, void* d_ws, size_t ws_size,
                              hipStream_t stream)
{
    const float* h      = (const float*)d_in[0];   // [2,2048,1024]
    const float* mask   = (const float*)d_in[1];   // [2,2048]
    const float* w_qkv  = (const float*)d_in[2];   // [1024,3072]
    const float* w_proj = (const float*)d_in[3];   // [1024,1024]
    const float* b_proj = (const float*)d_in[4];   // [1024]
    float* out = (float*)d_out;

    // ws layout (u16 units), ~42 MB total
    u16* qkv = (u16*)d_ws;                          // 3*BHND (bf16)
    u16* wqT = qkv + 3 * BHND;                      // 3072*1024 fp16
    u16* wpT = wqT + (size_t)3072 * 1024;           // 1024*1024 fp16
    u16* hA  = wpT + (size_t)1024 * 1024;           // 4096*1024 fp16 (h; later O)
    u16* oA  = hA;                                  // O aliases dead hA

    // prepasses: h -> fp16; W -> fp16 transposed
    prep_h_kernel<<<(MROWS * DIMC) / (256 * 8), 256, 0, stream>>>(h, hA);
    prep_w_kernel<<<dim3(16, 48), 256, 0, stream>>>(w_qkv, wqT, DIMC, 3 * DIMC);
    prep_w_kernel<<<dim3(16, 16), 256, 0, stream>>>(w_proj, wpT, DIMC, DIMC);

    // 1) qkv projection (fp16 MFMA) -> bf16 q(exp2-scaled)/k, masked v^T
    gemm_f16_kernel<0><<<dim3(24, 32), 256, 0, stream>>>(
        hA, wqT, nullptr, mask, nullptr, qkv, MROWS, 3 * DIMC, DIMC);

    // 2) MFMA flash attention -> fp16 O (over dead hA)
    attn_mfma_kernel<<<BATCH * NHEADS * (SEQ / 64), 256, 0, stream>>>(
        qkv, qkv + BHND, qkv + 2 * BHND, oA);

    // 3) output projection + bias (fp16 MFMA, fp32 out)
    gemm_f16_kernel<1><<<dim3(8, 32), 256, 0, stream>>>(
        oA, wpT, b_proj, nullptr, out, nullptr, MROWS, DIMC, DIMC);

    // 4) new_mask = sqrt(mask)
    mask_sqrt_kernel<<<(BATCH * SEQ + 255) / 256, 256, 0, stream>>>(
        mask, out + MROWS * DIMC, BATCH * SEQ);
}

// Round 13
// 164.315 us; speedup vs baseline: 1.5570x; 1.0365x over previous
//
#include <hip/hip_runtime.h>
#include <hip/hip_bf16.h>
#include <math.h>

#define DIMC   1024
#define NHEADS 16
#define HDIM   64
#define BATCH  2
#define SEQ    2048
#define SCALE  0.125f
// q pre-scale: SCALE * log2(e)  -> scores in exp2 domain
#define QSCL   (0.125f * 1.44269504088896341f)

typedef unsigned short u16;
typedef unsigned int   u32;
typedef __attribute__((ext_vector_type(8))) short bf16x8;    // 8 bf16 = 4 VGPRs
typedef _Float16 f16x8 __attribute__((ext_vector_type(8)));  // 8 fp16 = 4 VGPRs
typedef __attribute__((ext_vector_type(4))) float f32x4;

// [B][H][N][D] per tensor, element count
#define BHND ((size_t)BATCH * NHEADS * SEQ * HDIM)   // 4,194,304
#define MROWS ((size_t)BATCH * SEQ)                  // 4096

__device__ __forceinline__ u16 f2bf(float x) {
    __hip_bfloat16 h = __float2bfloat16(x);
    return *reinterpret_cast<u16*>(&h);
}
__device__ __forceinline__ u16 f2h(float x) {
    _Float16 h = (_Float16)x;
    return *reinterpret_cast<u16*>(&h);
}
__device__ __forceinline__ void gload_lds16(const u16* g, u16* l) {
    __builtin_amdgcn_global_load_lds(
        (const __attribute__((address_space(1))) unsigned int*)g,
        (__attribute__((address_space(3))) unsigned int*)l, 16, 0, 0);
}

// ---------------------------------------------------------------------------
// Prepass 1: h fp32 -> fp16 A [M][K]
// ---------------------------------------------------------------------------
__global__ __launch_bounds__(256) void prep_h_kernel(
    const float* __restrict__ in, u16* __restrict__ outh)
{
    int i = (blockIdx.x * 256 + threadIdx.x) * 8;
    float4 a = *(const float4*)&in[i];
    float4 b = *(const float4*)&in[i + 4];
    float v[8] = {a.x, a.y, a.z, a.w, b.x, b.y, b.z, b.w};
    bf16x8 o;
    #pragma unroll
    for (int j = 0; j < 8; ++j) o[j] = (short)f2h(v[j]);
    *(bf16x8*)&outh[i] = o;
}

// ---------------------------------------------------------------------------
// Prepass 2: W [K][N] fp32 -> transposed fp16 W^T [N][K]
// ---------------------------------------------------------------------------
__global__ __launch_bounds__(256) void prep_w_kernel(
    const float* __restrict__ W, u16* __restrict__ T, int K, int N)
{
    __shared__ float Ws[64][65];
    const int kb  = blockIdx.x * 64;
    const int nb  = blockIdx.y * 64;
    const int tid = threadIdx.x;
    const int jr  = (tid & 15) * 4;
    const int ir  = tid >> 4;
    #pragma unroll
    for (int it = 0; it < 4; ++it) {
        int i = ir + it * 16;
        *(float4*)&Ws[i][jr] = *(const float4*)&W[(size_t)(kb + i) * N + nb + jr];
    }
    __syncthreads();
    const int n  = tid >> 2;
    const int k0 = (tid & 3) * 16;
    bf16x8 h0, h1;
    #pragma unroll
    for (int kk = 0; kk < 8; ++kk) {
        h0[kk] = (short)f2h(Ws[k0 + kk][n]);
        h1[kk] = (short)f2h(Ws[k0 + 8 + kk][n]);
    }
    size_t off = (size_t)(nb + n) * K + kb + k0;
    *(bf16x8*)&T[off]     = h0;
    *(bf16x8*)&T[off + 8] = h1;
}

// ---------------------------------------------------------------------------
// fp16 MFMA GEMM (validated round 12). 128x128 tile, BK=32, 4 waves x (64x64),
// global_load_lds staging, one MFMA per fragment pair.
// MODE 0: scatter bf16 q(*QSCL, exp2 domain)/k [B][H][N][D],
//         v^T PRE-MASKED by mask[key] [B][H][D][N]
// MODE 1: + bias, fp32 store to out[M][N]
// ---------------------------------------------------------------------------
template <int MODE>
__global__ __launch_bounds__(256) void gemm_f16_kernel(
    const u16* __restrict__ A, const u16* __restrict__ B,
    const float* __restrict__ bias, const float* __restrict__ vmask,
    float* __restrict__ outf, u16* __restrict__ outb,
    int M, int N, int K)
{
    __shared__ __align__(16) u16 lds[2][128 * 32];   // A tile, B^T tile

    const int bm   = blockIdx.y * 128;
    const int bn   = blockIdx.x * 128;
    const int tid  = threadIdx.x;
    const int wid  = tid >> 6;
    const int lane = tid & 63;
    const int lo   = lane & 15;
    const int g4   = lane >> 4;
    const int wr   = wid >> 1, wc = wid & 1;

    const int mrow = lane >> 2;            // 0..15
    const int ks8  = (lane & 3) * 8;
    const u16* g0  = (wid < 2)
        ? A + (size_t)(bm + (wid & 1) * 64 + mrow) * K + ks8
        : B + (size_t)(bn + (wid & 1) * 64 + mrow) * K + ks8;
    u16* lbase = &lds[wid >> 1][(wid & 1) * 64 * 32];

    f32x4 acc[4][4] = {};

    for (int k0 = 0; k0 < K; k0 += 32) {
        const u16* g = g0 + k0;
        #pragma unroll
        for (int s = 0; s < 4; ++s)
            gload_lds16(g + (size_t)s * 16 * K, lbase + s * 512);
        __syncthreads();

        f16x8 bfr[4];
        #pragma unroll
        for (int ni = 0; ni < 4; ++ni)
            bfr[ni] = *(const f16x8*)&lds[1][(wc * 64 + ni * 16 + lo) * 32 + g4 * 8];
        #pragma unroll
        for (int mi = 0; mi < 4; ++mi) {
            f16x8 a = *(const f16x8*)&lds[0][(wr * 64 + mi * 16 + lo) * 32 + g4 * 8];
            #pragma unroll
            for (int ni = 0; ni < 4; ++ni)
                acc[mi][ni] = __builtin_amdgcn_mfma_f32_16x16x32_f16(a, bfr[ni], acc[mi][ni], 0, 0, 0);
        }
        __syncthreads();
    }

    if (MODE == 0) {
        #pragma unroll
        for (int mi = 0; mi < 4; ++mi) {
            int m0 = bm + wr * 64 + mi * 16 + 4 * g4;
            #pragma unroll
            for (int ni = 0; ni < 4; ++ni) {
                int n0    = bn + wc * 64 + ni * 16;
                int which = n0 >> 10;
                int head  = (n0 & 1023) >> 6;
                int d     = (n0 & 63) + lo;
                if (which == 0) {
                    #pragma unroll
                    for (int r = 0; r < 4; ++r) {
                        int m = m0 + r, b = m >> 11, seq = m & 2047;
                        outb[(((size_t)b * NHEADS + head) * SEQ + seq) * HDIM + d] =
                            f2bf(acc[mi][ni][r] * QSCL);
                    }
                } else if (which == 1) {
                    #pragma unroll
                    for (int r = 0; r < 4; ++r) {
                        int m = m0 + r, b = m >> 11, seq = m & 2047;
                        outb[BHND + (((size_t)b * NHEADS + head) * SEQ + seq) * HDIM + d] =
                            f2bf(acc[mi][ni][r]);
                    }
                } else {
                    int b = m0 >> 11, seq0 = m0 & 2047;   // r=0..3 same batch
                    float4 mv = *(const float4*)&vmask[b * SEQ + seq0];
                    ushort4 o;
                    o.x = f2bf(acc[mi][ni][0] * mv.x);
                    o.y = f2bf(acc[mi][ni][1] * mv.y);
                    o.z = f2bf(acc[mi][ni][2] * mv.z);
                    o.w = f2bf(acc[mi][ni][3] * mv.w);
                    *(ushort4*)&outb[2 * BHND +
                        (((size_t)b * NHEADS + head) * HDIM + d) * SEQ + seq0] = o;
                }
            }
        }
    } else {
        #pragma unroll
        for (int ni = 0; ni < 4; ++ni) {
            int col = bn + wc * 64 + ni * 16 + lo;
            float bv = bias[col];
            #pragma unroll
            for (int mi = 0; mi < 4; ++mi) {
                int m0 = bm + wr * 64 + mi * 16 + 4 * g4;
                #pragma unroll
                for (int r = 0; r < 4; ++r)
                    outf[(size_t)(m0 + r) * N + col] = acc[mi][ni][r] + bv;
            }
        }
    }
}

// ---------------------------------------------------------------------------
// MFMA flash attention. This round:
//  - T14 async-STAGE: K/V tile t+1 global loads issued right after the
//    compute barrier, consumed by next iteration's ds_writes -> HBM/L2
//    latency hides under QK^T/softmax/PV instead of serializing per tile.
//  - denominator via ones-MFMA: accl = mfma(pa, ones_reg, accl) gives the
//    UNMASKED sum of raw p (mask lives in V) directly in acc layout
//    (q = 4g+r) -> ps add-chain, lrun bookkeeping, and the epilogue
//    inv-shuffle all eliminated. Numerator/denominator share bf16-P
//    rounding (errors partially cancel in the ratio).
// ---------------------------------------------------------------------------
__global__ __launch_bounds__(256) void attn_mfma_kernel(
    const u16* __restrict__ qb, const u16* __restrict__ kb,
    const u16* __restrict__ vtb, u16* __restrict__ oA)
{
    __shared__ __align__(16) u16 Ks[64 * 64];       // [key][d] swizzled
    __shared__ __align__(16) u16 Vt[64 * 64];       // [d][key] swizzled
    __shared__ __align__(16) u16 Plds[4][16 * 72];  // [wave][q][key], pad 72

    const int bid  = blockIdx.x;          // 1024 = B*H*(SEQ/64)
    const int qt   = bid & 31;
    const int h    = (bid >> 5) & 15;
    const int b    = bid >> 9;
    const int tid  = threadIdx.x;
    const int wid  = tid >> 6;
    const int lane = tid & 63;
    const int lo   = lane & 15;
    const int g    = lane >> 4;

    const size_t bh = (size_t)b * NHEADS + h;
    const int qbase = qt * 64 + wid * 16;

    // Q fragment (B operand of swapped QK^T): col = q = qbase+lo
    const u16* qrowp = qb + (bh * SEQ + qbase + lo) * HDIM + 8 * g;
    const bf16x8 aq0 = *(const bf16x8*)(qrowp);
    const bf16x8 aq1 = *(const bf16x8*)(qrowp + 32);

    // staging: 64x64 tiles, thread -> row = tid>>2, two 8-elem slots
    const int srow  = tid >> 2;
    const int scol  = (tid & 3) * 16;
    const int swz   = (srow & 7) << 3;
    const int idx0  = srow * 64 + (scol ^ swz);
    const int idx1  = srow * 64 + ((scol + 8) ^ swz);
    const u16* kgp  = kb  + (bh * SEQ  + srow) * HDIM + scol;   // + k0*HDIM
    const u16* vgp  = vtb + (bh * HDIM + srow) * SEQ  + scol;   // + k0

    // hoisted LDS fragment offsets (loop-invariant)
    int kof0[4], kof1[4];
    #pragma unroll
    for (int kt = 0; kt < 4; ++kt) {
        int key  = lo + 16 * kt;
        int kbse = key * 64;
        int ksw  = (key & 7) << 3;
        kof0[kt] = kbse + ((8 * g) ^ ksw);
        kof1[kt] = kbse + ((32 + 8 * g) ^ ksw);
    }
    int vof0[4], vof1[4];
    #pragma unroll
    for (int dt = 0; dt < 4; ++dt) {
        int vbse = (lo + 16 * dt) * 64;
        int vsw  = (lo & 7) << 3;
        vof0[dt] = vbse + ((8 * g) ^ vsw);
        vof1[dt] = vbse + ((32 + 8 * g) ^ vsw);
    }

    // all-ones bf16 B-fragment (register constant) for the denominator MFMA
    bf16x8 ones;
    #pragma unroll
    for (int j = 0; j < 8; ++j) ones[j] = (short)0x3F80;

    f32x4 acc[4] = {};            // O[q = 4g+r][d = 16dt+lo]
    f32x4 accl = {};              // denominator l[q = 4g+r] (all lo identical)
    float mrun = -1e30f;          // running max for q = lo (exp2 domain)

    u16* pw = &Plds[wid][0];

    // T14 prologue: tile 0 -> registers
    bf16x8 rk0 = *(const bf16x8*)(kgp);
    bf16x8 rk1 = *(const bf16x8*)(kgp + 8);
    bf16x8 rv0 = *(const bf16x8*)(vgp);
    bf16x8 rv1 = *(const bf16x8*)(vgp + 8);

    for (int k0 = 0; k0 < SEQ; k0 += 64) {
        __syncthreads();                    // prev tile's LDS reads done
        *(bf16x8*)&Ks[idx0] = rk0;
        *(bf16x8*)&Ks[idx1] = rk1;
        *(bf16x8*)&Vt[idx0] = rv0;
        *(bf16x8*)&Vt[idx1] = rv1;
        __syncthreads();                    // tile ready
        if (k0 + 64 < SEQ) {                // issue next-tile loads, no wait
            const u16* kn = kgp + (size_t)(k0 + 64) * HDIM;
            rk0 = *(const bf16x8*)(kn);
            rk1 = *(const bf16x8*)(kn + 8);
            rv0 = *(const bf16x8*)(vgp + k0 + 64);
            rv1 = *(const bf16x8*)(vgp + k0 + 64 + 8);
        }

        // swapped QK^T: s[kt][r] = S^T[key = 16kt+4g+r][q = lo]
        f32x4 s[4];
        #pragma unroll
        for (int kt = 0; kt < 4; ++kt) {
            f32x4 t = {};
            t = __builtin_amdgcn_mfma_f32_16x16x32_bf16(*(const bf16x8*)&Ks[kof0[kt]], aq0, t, 0, 0, 0);
            t = __builtin_amdgcn_mfma_f32_16x16x32_bf16(*(const bf16x8*)&Ks[kof1[kt]], aq1, t, 0, 0, 0);
            s[kt] = t;
        }

        // row max for q = lo: in-lane tree + 2 shfl_xor
        float m01 = fmaxf(fmaxf(s[0][0], s[0][1]), fmaxf(s[0][2], s[0][3]));
        float m23 = fmaxf(fmaxf(s[1][0], s[1][1]), fmaxf(s[1][2], s[1][3]));
        float m45 = fmaxf(fmaxf(s[2][0], s[2][1]), fmaxf(s[2][2], s[2][3]));
        float m67 = fmaxf(fmaxf(s[3][0], s[3][1]), fmaxf(s[3][2], s[3][3]));
        float rm  = fmaxf(fmaxf(m01, m23), fmaxf(m45, m67));
        rm = fmaxf(rm, __shfl_xor(rm, 16));
        rm = fmaxf(rm, __shfl_xor(rm, 32));

        if (!__all(rm <= mrun)) {            // bit-exact skip (corr==1 if skipped)
            float mnew = fmaxf(mrun, rm);
            float corr = exp2f(mrun - mnew);
            mrun = mnew;
            #pragma unroll
            for (int r = 0; r < 4; ++r) {
                float cq = __shfl(corr, 4 * g + r);   // corr for q = 4g+r
                accl[r] *= cq;
                #pragma unroll
                for (int dt = 0; dt < 4; ++dt) acc[dt][r] *= cq;
            }
        }

        // p = exp2(s - m), raw (mask folded into V); pack -> P in LDS
        #pragma unroll
        for (int kt = 0; kt < 4; ++kt) {
            ushort4 o;
            o.x = f2bf(exp2f(s[kt][0] - mrun));
            o.y = f2bf(exp2f(s[kt][1] - mrun));
            o.z = f2bf(exp2f(s[kt][2] - mrun));
            o.w = f2bf(exp2f(s[kt][3] - mrun));
            *(ushort4*)&pw[lo * 72 + 16 * kt + 4 * g] = o;
        }

        // PV + denominator (same-wave DS ops in-order)
        const bf16x8 pa0 = *(const bf16x8*)&pw[lo * 72 + 8 * g];
        const bf16x8 pa1 = *(const bf16x8*)&pw[lo * 72 + 32 + 8 * g];
        accl = __builtin_amdgcn_mfma_f32_16x16x32_bf16(pa0, ones, accl, 0, 0, 0);
        accl = __builtin_amdgcn_mfma_f32_16x16x32_bf16(pa1, ones, accl, 0, 0, 0);
        #pragma unroll
        for (int dt = 0; dt < 4; ++dt) {
            acc[dt] = __builtin_amdgcn_mfma_f32_16x16x32_bf16(pa0, *(const bf16x8*)&Vt[vof0[dt]], acc[dt], 0, 0, 0);
            acc[dt] = __builtin_amdgcn_mfma_f32_16x16x32_bf16(pa1, *(const bf16x8*)&Vt[vof1[dt]], acc[dt], 0, 0, 0);
        }
    }

    // epilogue: 1/l already in acc layout; single fp16 O for the proj GEMM
    #pragma unroll
    for (int r = 0; r < 4; ++r) {
        float invq = 1.f / accl[r];
        size_t row = (size_t)b * SEQ + qbase + 4 * g + r;
        u16* dst = oA + row * DIMC + h * HDIM + lo;
        #pragma unroll
        for (int dt = 0; dt < 4; ++dt)
            dst[16 * dt] = f2h(acc[dt][r] * invq);
    }
}

__global__ void mask_sqrt_kernel(const float* __restrict__ mask,
                                 float* __restrict__ out, int n)
{
    int i = blockIdx.x * 256 + threadIdx.x;
    if (i < n) out[i] = sqrtf(mask[i]);
}

// ---------------------------------------------------------------------------
extern "C" void kernel_launch(void* const* d_in, const int* in_sizes, int n_in,
                              void* d_out, int out_size, void* d_ws, size_t ws_size,
                              hipStream_t stream)
{
    const float* h      = (const float*)d_in[0];   // [2,2048,1024]
    const float* mask   = (const float*)d_in[1];   // [2,2048]
    const float* w_qkv  = (const float*)d_in[2];   // [1024,3072]
    const float* w_proj = (const float*)d_in[3];   // [1024,1024]
    const float* b_proj = (const float*)d_in[4];   // [1024]
    float* out = (float*)d_out;

    // ws layout (u16 units), ~42 MB total
    u16* qkv = (u16*)d_ws;                          // 3*BHND (bf16)
    u16* wqT = qkv + 3 * BHND;                      // 3072*1024 fp16
    u16* wpT = wqT + (size_t)3072 * 1024;           // 1024*1024 fp16
    u16* hA  = wpT + (size_t)1024 * 1024;           // 4096*1024 fp16 (h; later O)
    u16* oA  = hA;                                  // O aliases dead hA

    // prepasses: h -> fp16; W -> fp16 transposed
    prep_h_kernel<<<(MROWS * DIMC) / (256 * 8), 256, 0, stream>>>(h, hA);
    prep_w_kernel<<<dim3(16, 48), 256, 0, stream>>>(w_qkv, wqT, DIMC, 3 * DIMC);
    prep_w_kernel<<<dim3(16, 16), 256, 0, stream>>>(w_proj, wpT, DIMC, DIMC);

    // 1) qkv projection (fp16 MFMA) -> bf16 q(exp2-scaled)/k, masked v^T
    gemm_f16_kernel<0><<<dim3(24, 32), 256, 0, stream>>>(
        hA, wqT, nullptr, mask, nullptr, qkv, MROWS, 3 * DIMC, DIMC);

    // 2) MFMA flash attention (T14 async stage + ones-MFMA denominator)
    attn_mfma_kernel<<<BATCH * NHEADS * (SEQ / 64), 256, 0, stream>>>(
        qkv, qkv + BHND, qkv + 2 * BHND, oA);

    // 3) output projection + bias (fp16 MFMA, fp32 out)
    gemm_f16_kernel<1><<<dim3(8, 32), 256, 0, stream>>>(
        oA, wpT, b_proj, nullptr, out, nullptr, MROWS, DIMC, DIMC);

    // 4) new_mask = sqrt(mask)
    mask_sqrt_kernel<<<(BATCH * SEQ + 255) / 256, 256, 0, stream>>>(
        mask, out + MROWS * DIMC, BATCH * SEQ);
}